// Round 17
// baseline (508.377 us; speedup 1.0000x reference)
//
#include <hip/hip_runtime.h>
#include <stdint.h>

// ---------------------------------------------------------------------------
// RGNN layer: h_t = relu( sum_k L^{k+1} (x_t W_k + h_{t-1} H_k) ), h_{-1}=0
// B=8 T=16 N=1024 F=128 K=4.
//
//   Lcat [1024 n][4096 q],  q=(k,m):  Lcat[n][k*1024+m] = (L^{k+1})[n][m]
//   S    [8192 c=(b,m)][4096 q]     : S layout S[b][g][k][m]
//   Z[n][(b,g)] = sum_q Lcat[n][q] * S[..]; h = relu(Z); out = h (f32)
//
// Laws (r4,7,8,11,12,14,15,16): LDS staging mandatory; no in-kernel
// cross-block fences; 16x16 frags conflict-free w/ XOR swizzle; 64x64 wave
// tiles optimal; setprio neutral; combine fusion loses; GRAPH GEMM IS
// L2-BW-BOUND: traffic = GZ*(GX*Aslice + GY*Bslice); r16 = 576 MB/step =
// 16.7us floor at 34.5 TB/s, measured 17.5 (1.05x) -> reduce re-reads.
//
// Round 17: graph tile 256x128 (8 waves, 4x2 grid of 64x64 wave tiles,
// 512 threads, 96KB LDS, grid 8x4x8 = 256 WG, slice z == XCD z's 32 CUs).
// B re-reads 8->4: traffic 320 MB/step -> 9.3us floor. Rest = round 16.
// ---------------------------------------------------------------------------

typedef __bf16 bf16_t;
typedef __bf16 bf16x4 __attribute__((ext_vector_type(4)));
typedef __bf16 bf16x8 __attribute__((ext_vector_type(8)));
typedef float  f32x4  __attribute__((ext_vector_type(4)));

__device__ __forceinline__ void gload_lds16(const void* g, void* l) {
    __builtin_amdgcn_global_load_lds(
        (const __attribute__((address_space(1))) void*)g,
        (__attribute__((address_space(3))) void*)l,
        16, 0, 0);
}

template<int N> __device__ __forceinline__ void wait_vmcnt() {
    if constexpr (N == 0)       asm volatile("s_waitcnt vmcnt(0)" ::: "memory");
    else if constexpr (N == 2)  asm volatile("s_waitcnt vmcnt(2)" ::: "memory");
    else if constexpr (N == 3)  asm volatile("s_waitcnt vmcnt(3)" ::: "memory");
    else if constexpr (N == 4)  asm volatile("s_waitcnt vmcnt(4)" ::: "memory");
    else if constexpr (N == 6)  asm volatile("s_waitcnt vmcnt(6)" ::: "memory");
    else if constexpr (N == 8)  asm volatile("s_waitcnt vmcnt(8)" ::: "memory");
    else                        asm volatile("s_waitcnt vmcnt(16)" ::: "memory");
}

// ---- merged setup: L->Lcat/Lt, W/H->WHT, x->bf16 (r14-validated) -----------
// grid 8448: [0,4096) L, [4096,4352) WH (65536 elems), [4352,8448) x.

__global__ void k_setup(const float* __restrict__ x, const float* __restrict__ L,
                        const float* __restrict__ W, const float* __restrict__ H,
                        bf16_t* __restrict__ xb, bf16_t* __restrict__ Lcat,
                        bf16_t* __restrict__ Lt, bf16_t* __restrict__ WHT) {
    int bid = blockIdx.x;
    if (bid < 4096) {                       // L: 1024x1024
        int idx = bid * 256 + threadIdx.x;
        int n = idx >> 10, m = idx & 1023;
        float v = L[idx];
        Lcat[n * 4096 + m] = (bf16_t)v;
        Lt[m * 1024 + n]   = (bf16_t)v;
    } else if (bid < 4352) {                // WH: 4*128*128 = 65536
        int idx = (bid - 4096) * 256 + threadIdx.x;
        int k = idx >> 14, f = (idx >> 7) & 127, g = idx & 127;
        WHT[(k * 128 + g) * 256 + f]       = (bf16_t)W[idx];
        WHT[(k * 128 + g) * 256 + 128 + f] = (bf16_t)H[idx];
    } else {                                // x: 4194304 float4, grid-stride
        int i = (bid - 4352) * 256 + threadIdx.x;
        for (; i < 4194304; i += 4096 * 256) {
            float4 v = reinterpret_cast<const float4*>(x)[i];
            bf16x4 o = { (bf16_t)v.x, (bf16_t)v.y, (bf16_t)v.z, (bf16_t)v.w };
            reinterpret_cast<bf16x4*>(xb)[i] = o;
        }
    }
}

// ---- combine: Z = relu(sum_{z<8} Zp_bf16[z]) -> h bf16, out f32 ------------

__global__ __launch_bounds__(256)
void k_combine8(const bf16_t* __restrict__ Zp,  // [8][1024][1024] (n, c=(b,g))
                bf16_t* __restrict__ h, float* __restrict__ out, int t) {
    int i = blockIdx.x * 256 + threadIdx.x;
    int n  = i >> 7;
    int c8 = (i & 127) * 8;
    size_t o = (size_t)n * 1024 + c8;
    float s[8] = {};
    #pragma unroll
    for (int z = 0; z < 8; ++z) {
        bf16x8 v = *reinterpret_cast<const bf16x8*>(Zp + (size_t)z * 1048576 + o);
        #pragma unroll
        for (int j = 0; j < 8; ++j) s[j] += (float)v[j];
    }
    bf16x8 hb;
    float4 o0, o1;
    #pragma unroll
    for (int j = 0; j < 8; ++j) { s[j] = fmaxf(s[j], 0.f); hb[j] = (bf16_t)s[j]; }
    o0.x = s[0]; o0.y = s[1]; o0.z = s[2]; o0.w = s[3];
    o1.x = s[4]; o1.y = s[5]; o1.z = s[6]; o1.w = s[7];
    int b = c8 >> 7, g = c8 & 127;
    *reinterpret_cast<bf16x8*>(h + (size_t)b * 131072 + (size_t)n * 128 + g) = hb;
    float* op = out + (size_t)b * 2097152 + (size_t)t * 131072
                    + (size_t)n * 128 + g;
    *reinterpret_cast<float4*>(op)     = o0;
    *reinterpret_cast<float4*>(op + 4) = o1;
}

// ---- GEMM body (16x16x32 MFMA, counted-vmcnt pipeline, NBUF=2 or 3) --------
// C[M][N] = A[M][KTOT] @ B[KTOT][N], B given as B^T rows (N rows, K contig).
// WVMxWVN waves, wave tile (BM/WVM)x(BN/WVN). Grid 1D, bijective XCD swizzle.
// EPI: 0 plain bf16   1 S-layout bf16   2 relu h+out   3 bf16 partial Zp[bz]
//      4 chain1: Lcat col 1024+ AND transposed copy into (bf16*)Cf
//      6 chain2: Lcat col 2048 + kb_*1024
// BADDR: 0 = BT rows; 1 = feature split x|h; 2 = chain2 (kb_ picks BT/B2).
// ZK: per-bz K offset.
template<int BM, int BN, int GX, int GY, int GZ, int KTOT,
         int EPI, int BADDR, int ZK, int DEC, int NBUF,
         int WVM = 2, int WVN = 2>
__device__ __forceinline__
void gemm_body(const bf16_t* __restrict__ A, int lda,
               const bf16_t* __restrict__ BT, int ldbt,
               const bf16_t* __restrict__ B2,
               bf16_t* __restrict__ Cb, float* __restrict__ Cf,
               int ldc, int t)
{
    constexpr int BK = 64;
    constexpr int NTH = WVM * WVN * 64;    // threads per block
    constexpr int WM = BM / WVM, WN = BN / WVN;
    constexpr int MF = WM / 16, NF = WN / 16;
    constexpr int NT = KTOT / BK;
    constexpr int NWG = GX * GY * GZ;
    constexpr int ACH = BM * 8;            // 16B chunks per A tile
    constexpr int BCH = BN * 8;
    constexpr int LPT = (ACH + BCH) / NTH;

    __shared__ __align__(16) bf16_t As[NBUF][BM * BK];
    __shared__ __align__(16) bf16_t Bs[NBUF][BN * BK];

    const int tid  = threadIdx.x;
    const int lane = tid & 63;
    const int wave = tid >> 6;
    const int wm = wave / WVN, wn = wave % WVN;

    const int id  = blockIdx.x;
    const int swz = (id & 7) * (NWG / 8) + (id >> 3);
    int bx, by, bz;
    if (DEC == 0) {
        bx = swz % GX; by = (swz / GX) % GY; bz = swz / (GX * GY);
    } else {
        by = swz % GY; bz = (swz / GY) % GZ; bx = swz / (GY * GZ);
    }

    const int m0 = by * BM;
    const int c0 = bx * BN;
    const int kb_ = bz;

    const bf16_t* Ap = (EPI == 1) ? (A + kb_ * 128 * 256) : A;

    f32x4 acc[MF][NF] = {};

    auto stage = [&](int bufi, int kt) {
        const int q0 = kt * BK + (ZK > 0 ? kb_ * ZK : 0);
        #pragma unroll
        for (int i = 0; i < ACH / NTH; ++i) {
            int chunk = i * NTH + tid;
            int off = chunk * 16;
            int row = off >> 7;
            int kel = ((off ^ ((row & 7) << 4)) & 127) >> 1;
            const bf16_t* src = Ap + (size_t)(m0 + row) * lda + (q0 + kel);
            gload_lds16(src, (char*)(&As[bufi][0]) + off);
        }
        #pragma unroll
        for (int i = 0; i < BCH / NTH; ++i) {
            int chunk = i * NTH + tid;
            int off = chunk * 16;
            int row = off >> 7;
            int kel = ((off ^ ((row & 7) << 4)) & 127) >> 1;
            int c = c0 + row;
            const bf16_t* src;
            if (BADDR == 0) {
                src = BT + (size_t)c * ldbt + (q0 + kel);
            } else if (BADDR == 2) {
                const bf16_t* bt = (kb_ == 0) ? BT : B2;
                src = bt + (size_t)c * ldbt + (q0 + kel);
            } else {
                int f = q0 + kel;
                if (q0 < 128) {
                    src = BT + (size_t)(c >> 10) * 2097152
                             + (size_t)t * 131072
                             + (size_t)(c & 1023) * 128 + f;
                } else {
                    src = B2 + (size_t)c * 128 + (f - 128);
                }
            }
            gload_lds16(src, (char*)(&Bs[bufi][0]) + off);
        }
    };

    auto compute = [&](int cur) {
        #pragma unroll
        for (int kk = 0; kk < 2; ++kk) {
            bf16x8 af[MF], bfr[NF];
            const int klane = (kk * 32 + (lane >> 4) * 8) * 2;
            #pragma unroll
            for (int mf = 0; mf < MF; ++mf) {
                int row = wm * WM + mf * 16 + (lane & 15);
                int bo = (row * 128 + klane) ^ ((row & 7) << 4);
                af[mf] = *reinterpret_cast<const bf16x8*>(
                             (const char*)(&As[cur][0]) + bo);
            }
            #pragma unroll
            for (int nf = 0; nf < NF; ++nf) {
                int row = wn * WN + nf * 16 + (lane & 15);
                int bo = (row * 128 + klane) ^ ((row & 7) << 4);
                bfr[nf] = *reinterpret_cast<const bf16x8*>(
                              (const char*)(&Bs[cur][0]) + bo);
            }
            #pragma unroll
            for (int mf = 0; mf < MF; ++mf)
                #pragma unroll
                for (int nf = 0; nf < NF; ++nf)
                    acc[mf][nf] = __builtin_amdgcn_mfma_f32_16x16x32_bf16(
                        af[mf], bfr[nf], acc[mf][nf], 0, 0, 0);
        }
    };

    if constexpr (NBUF == 3) {
        stage(0, 0);
        stage(1, 1);
        for (int kt = 0; kt < NT; ++kt) {
            if (kt < NT - 1) wait_vmcnt<LPT>(); else wait_vmcnt<0>();
            __builtin_amdgcn_s_barrier();
            __builtin_amdgcn_sched_barrier(0);
            if (kt + 2 < NT) stage((kt + 2) % 3, kt + 2);
            compute(kt % 3);
            __builtin_amdgcn_sched_barrier(0);
        }
    } else {
        stage(0, 0);
        stage(1, 1);
        for (int kt = 0; kt < NT; ++kt) {
            if (kt > 0 && kt + 1 < NT) {
                __builtin_amdgcn_s_barrier();
                stage((kt + 1) & 1, kt + 1);
            }
            if (kt + 1 < NT) wait_vmcnt<LPT>();
            else             wait_vmcnt<0>();
            __builtin_amdgcn_s_barrier();
            __builtin_amdgcn_sched_barrier(0);
            compute(kt & 1);
            __builtin_amdgcn_sched_barrier(0);
        }
    }

    // epilogue: 16x16 D map col=lane&15, row=(lane>>4)*4+r  [m89-verified]
    #pragma unroll
    for (int mf = 0; mf < MF; ++mf) {
        #pragma unroll
        for (int nf = 0; nf < NF; ++nf) {
            f32x4 v = acc[mf][nf];
            int col   = c0 + wn * WN + nf * 16 + (lane & 15);
            int rbase = m0 + wm * WM + mf * 16 + ((lane >> 4) * 4);
            if constexpr (EPI == 4) {
                bf16x4 tv;
                #pragma unroll
                for (int r = 0; r < 4; ++r) {
                    float val = v[r];
                    Cb[(size_t)(rbase + r) * 4096 + 1024 + col] = (bf16_t)val;
                    tv[r] = (bf16_t)val;
                }
                *reinterpret_cast<bf16x4*>(
                    (bf16_t*)Cf + (size_t)col * 1024 + rbase) = tv;
            } else {
                #pragma unroll
                for (int r = 0; r < 4; ++r) {
                    int row = rbase + r;
                    float val = v[r];
                    if (EPI == 0) {
                        Cb[(size_t)row * ldc + col] = (bf16_t)val;
                    } else if (EPI == 1) {
                        Cb[(size_t)(col >> 10) * 524288 + (size_t)row * 4096
                           + (size_t)kb_ * 1024 + (col & 1023)] = (bf16_t)val;
                    } else if (EPI == 2) {
                        val = fmaxf(val, 0.f);
                        int b = col >> 7, g = col & 127;
                        Cb[(size_t)b * 131072 + (size_t)row * 128 + g]
                            = (bf16_t)val;
                        Cf[(size_t)b * 2097152 + (size_t)t * 131072
                           + (size_t)row * 128 + g] = val;
                    } else if (EPI == 3) {
                        Cb[(size_t)kb_ * 1048576 + (size_t)row * 1024 + col]
                            = (bf16_t)val;
                    } else {
                        // EPI == 6: chain2 -> Lcat cols 2048 + kb_*1024
                        Cb[(size_t)row * 4096 + 2048 + kb_ * 1024 + col]
                            = (bf16_t)val;
                    }
                }
            }
        }
    }
}

// ---- flavor wrappers --------------------------------------------------------

__global__ __launch_bounds__(256)
void k_chain(const bf16_t* __restrict__ A, const bf16_t* __restrict__ BT,
             bf16_t* __restrict__ Cb) {
    gemm_body<64, 64, 16, 16, 1, 1024, 0, 0, 0, 0, 3>(
        A, 4096, BT, 1024, nullptr, Cb, nullptr, 4096, 0);
}

__global__ __launch_bounds__(256)
void k_chain1(const bf16_t* __restrict__ Lcat, const bf16_t* __restrict__ Lt,
              bf16_t* __restrict__ Cb, bf16_t* __restrict__ Lt2) {
    // L^2 = L @ L -> Lcat cols [1024,2048) + Lt2 = (L^2)^T; grid 256
    gemm_body<64, 64, 16, 16, 1, 1024, 4, 0, 0, 0, 3>(
        Lcat, 4096, Lt, 1024, nullptr, Cb, (float*)Lt2, 0, 0);
}

__global__ __launch_bounds__(256)
void k_chain2(const bf16_t* __restrict__ A, const bf16_t* __restrict__ Lt,
              const bf16_t* __restrict__ Lt2, bf16_t* __restrict__ Cb) {
    // bz=0: L^3 = L^2 @ L;  bz=1: L^4 = L^2 @ L^2; grid 512 (2 blk/CU)
    gemm_body<64, 64, 16, 16, 2, 1024, 6, 2, 0, 0, 3>(
        A, 4096, Lt, 1024, Lt2, Cb, nullptr, 0, 0);
}

__global__ __launch_bounds__(256)
void k_feat(const bf16_t* __restrict__ WHT, const bf16_t* __restrict__ xb,
            const bf16_t* __restrict__ h, bf16_t* __restrict__ Sbuf, int t) {
    // M=128,N=8192,K=256 per tap; 128x64 tiles, grid 128*1*4 = 512
    gemm_body<128, 64, 128, 1, 4, 256, 1, 1, 0, 1, 3>(
        WHT, 256, xb, 0, h, Sbuf, nullptr, 0, t);
}

__global__ __launch_bounds__(512)
void k_graph(const bf16_t* __restrict__ Lcat, const bf16_t* __restrict__ Sbuf,
             bf16_t* __restrict__ Zp) {
    // M=1024,N=1024, split-K=8 (K=512/slice, slice z == XCD z);
    // 256x128 tiles, 8 waves (4x2 of 64x64), grid 8*4*8 = 256 @ 512 thr,
    // 96KB LDS, 2-buf counted vmcnt, bf16 partials.
    gemm_body<256, 128, 8, 4, 8, 512, 3, 0, 512, 0, 2, 4, 2>(
        Lcat, 4096, Sbuf, 4096, nullptr, Zp, nullptr, 0, 0);
}

__global__ __launch_bounds__(256)
void k_graph_ns(const bf16_t* __restrict__ Lcat, const bf16_t* __restrict__ Sbuf,
                bf16_t* __restrict__ h, float* __restrict__ out, int t) {
    // fallback: no split-K, K=4096; 128x128 tiles, grid 64, 3-buf
    gemm_body<128, 128, 8, 8, 1, 4096, 2, 0, 0, 0, 3>(
        Lcat, 4096, Sbuf, 4096, nullptr, h, out, 0, t);
}

// ---- launch ---------------------------------------------------------------

extern "C" void kernel_launch(void* const* d_in, const int* in_sizes, int n_in,
                              void* d_out, int out_size, void* d_ws, size_t ws_size,
                              hipStream_t stream) {
    const float* x = (const float*)d_in[0];   // [8][16][1024][128]
    const float* L = (const float*)d_in[1];   // [1024][1024]
    const float* W = (const float*)d_in[2];   // [4][128][128]
    const float* H = (const float*)d_in[3];   // [4][128][128]
    float* out = (float*)d_out;               // [8][16][1024][128]

    char* ws = (char*)d_ws;
    bf16_t* xb   = (bf16_t*)(ws);              // 33,554,432 B
    bf16_t* Lcat = (bf16_t*)(ws + 33554432);   //  8,388,608 B [1024][4096]
    bf16_t* Lt   = (bf16_t*)(ws + 41943040);   //  2,097,152 B
    bf16_t* WHT  = (bf16_t*)(ws + 44040192);   //    262,144 B
    bf16_t* Sbuf = (bf16_t*)(ws + 44302336);   //  8,388,608 B (S layout)
    bf16_t* h    = (bf16_t*)(ws + 52690944);   //  2,097,152 B
    bf16_t* Zp   = (bf16_t*)(ws + 54788096);   // 16,777,216 B [8][1024][1024]
    bf16_t* Lt2  = (bf16_t*)(ws + 71565312);   //  2,097,152 B (L^2)^T
    if (ws_size < 54788096u) return;
    const bool bigws = (ws_size >= 73662464u);

    hipMemsetAsync(h, 0, 2097152, stream);
    k_setup<<<8448, 256, 0, stream>>>(x, L, W, H, xb, Lcat, Lt, WHT);

    if (bigws) {
        // chain: L^2 (+transpose), then {L^3, L^4} concurrently
        k_chain1<<<256, 256, 0, stream>>>(Lcat, Lt, Lcat, Lt2);
        k_chain2<<<512, 256, 0, stream>>>(Lcat + 1024, Lt, Lt2, Lcat);
        for (int t = 0; t < 16; ++t) {
            // feature: S_k = WHT_k @ [x_t | h]^T, 512 WGs
            k_feat<<<512, 256, 0, stream>>>(WHT, xb, h, Sbuf, t);
            // graph: Zp[z] = Lcat[:,z*512:+512] @ S[z], 256 WGs @ 512 thr
            k_graph<<<256, 512, 0, stream>>>(Lcat, Sbuf, Zp);
            // combine: relu(sum Zp) -> h, out
            k_combine8<<<512, 256, 0, stream>>>(Zp, h, out, t);
        }
    } else {
        for (int p = 1; p < 4; ++p) {
            k_chain<<<256, 256, 0, stream>>>(Lcat + (p - 1) * 1024, Lt,
                                             Lcat + p * 1024);
        }
        for (int t = 0; t < 16; ++t) {
            k_feat<<<512, 256, 0, stream>>>(WHT, xb, h, Sbuf, t);
            k_graph_ns<<<64, 256, 0, stream>>>(Lcat, Sbuf, h, out, t);
        }
    }
}

// Round 18
// 493.075 us; speedup vs baseline: 1.0310x; 1.0310x over previous
//
#include <hip/hip_runtime.h>
#include <stdint.h>

// ---------------------------------------------------------------------------
// RGNN layer: h_t = relu( sum_k L^{k+1} (x_t W_k + h_{t-1} H_k) ), h_{-1}=0
// B=8 T=16 N=1024 F=128 K=4.
//
//   Lcat [1024 n][4096 q],  q=(k,m):  Lcat[n][k*1024+m] = (L^{k+1})[n][m]
//   S    [8192 c=(b,m)][4096 q]     : S layout S[b][g][k][m]
//   Z[n][(b,g)] = sum_q Lcat[n][q] * S[..]; h = relu(Z); out = h (f32)
//
// Final laws (r4,7,8,11,12,13-15,16,17):
//  - LDS staging mandatory (register-direct doubles L2 traffic, 2.6x loss)
//  - no in-kernel cross-block fences (buffer_wbl2/inv storm, 10x loss)
//  - 16x16 frags conflict-free w/ XOR swizzle (32x32 = structural 4-way)
//  - graph GEMM optimum: 128^2 tile / 64^2 waves / split-K=8 / 2-buf /
//    2 blk/CU. NOT L2-BW-bound (r17: halved traffic, no gain) and NOT
//    schedule-bound (r3/r12 null) — interior latency at this geometry.
//  - combine-into-feat fusion loses (r13-15); dispatch gaps are cheap.
//  - consolidated setup (1 dispatch) + chain as {L^2(+T), L^3||L^4}.
// This is the round-16 configuration — measured best (494.7us, absmax 10240).
// ---------------------------------------------------------------------------

typedef __bf16 bf16_t;
typedef __bf16 bf16x4 __attribute__((ext_vector_type(4)));
typedef __bf16 bf16x8 __attribute__((ext_vector_type(8)));
typedef float  f32x4  __attribute__((ext_vector_type(4)));

__device__ __forceinline__ void gload_lds16(const void* g, void* l) {
    __builtin_amdgcn_global_load_lds(
        (const __attribute__((address_space(1))) void*)g,
        (__attribute__((address_space(3))) void*)l,
        16, 0, 0);
}

template<int N> __device__ __forceinline__ void wait_vmcnt() {
    if constexpr (N == 0)       asm volatile("s_waitcnt vmcnt(0)" ::: "memory");
    else if constexpr (N == 2)  asm volatile("s_waitcnt vmcnt(2)" ::: "memory");
    else if constexpr (N == 3)  asm volatile("s_waitcnt vmcnt(3)" ::: "memory");
    else if constexpr (N == 4)  asm volatile("s_waitcnt vmcnt(4)" ::: "memory");
    else if constexpr (N == 6)  asm volatile("s_waitcnt vmcnt(6)" ::: "memory");
    else if constexpr (N == 8)  asm volatile("s_waitcnt vmcnt(8)" ::: "memory");
    else                        asm volatile("s_waitcnt vmcnt(16)" ::: "memory");
}

// ---- merged setup: L->Lcat/Lt, W/H->WHT, x->bf16 ---------------------------
// grid 8448: [0,4096) L, [4096,4352) WH (65536 elems), [4352,8448) x.

__global__ void k_setup(const float* __restrict__ x, const float* __restrict__ L,
                        const float* __restrict__ W, const float* __restrict__ H,
                        bf16_t* __restrict__ xb, bf16_t* __restrict__ Lcat,
                        bf16_t* __restrict__ Lt, bf16_t* __restrict__ WHT) {
    int bid = blockIdx.x;
    if (bid < 4096) {                       // L: 1024x1024
        int idx = bid * 256 + threadIdx.x;
        int n = idx >> 10, m = idx & 1023;
        float v = L[idx];
        Lcat[n * 4096 + m] = (bf16_t)v;
        Lt[m * 1024 + n]   = (bf16_t)v;
    } else if (bid < 4352) {                // WH: 4*128*128 = 65536
        int idx = (bid - 4096) * 256 + threadIdx.x;
        int k = idx >> 14, f = (idx >> 7) & 127, g = idx & 127;
        WHT[(k * 128 + g) * 256 + f]       = (bf16_t)W[idx];
        WHT[(k * 128 + g) * 256 + 128 + f] = (bf16_t)H[idx];
    } else {                                // x: 4194304 float4, grid-stride
        int i = (bid - 4352) * 256 + threadIdx.x;
        for (; i < 4194304; i += 4096 * 256) {
            float4 v = reinterpret_cast<const float4*>(x)[i];
            bf16x4 o = { (bf16_t)v.x, (bf16_t)v.y, (bf16_t)v.z, (bf16_t)v.w };
            reinterpret_cast<bf16x4*>(xb)[i] = o;
        }
    }
}

// ---- combine: Z = relu(sum_{z<8} Zp_bf16[z]) -> h bf16, out f32 ------------

__global__ __launch_bounds__(256)
void k_combine8(const bf16_t* __restrict__ Zp,  // [8][1024][1024] (n, c=(b,g))
                bf16_t* __restrict__ h, float* __restrict__ out, int t) {
    int i = blockIdx.x * 256 + threadIdx.x;
    int n  = i >> 7;
    int c8 = (i & 127) * 8;
    size_t o = (size_t)n * 1024 + c8;
    float s[8] = {};
    #pragma unroll
    for (int z = 0; z < 8; ++z) {
        bf16x8 v = *reinterpret_cast<const bf16x8*>(Zp + (size_t)z * 1048576 + o);
        #pragma unroll
        for (int j = 0; j < 8; ++j) s[j] += (float)v[j];
    }
    bf16x8 hb;
    float4 o0, o1;
    #pragma unroll
    for (int j = 0; j < 8; ++j) { s[j] = fmaxf(s[j], 0.f); hb[j] = (bf16_t)s[j]; }
    o0.x = s[0]; o0.y = s[1]; o0.z = s[2]; o0.w = s[3];
    o1.x = s[4]; o1.y = s[5]; o1.z = s[6]; o1.w = s[7];
    int b = c8 >> 7, g = c8 & 127;
    *reinterpret_cast<bf16x8*>(h + (size_t)b * 131072 + (size_t)n * 128 + g) = hb;
    float* op = out + (size_t)b * 2097152 + (size_t)t * 131072
                    + (size_t)n * 128 + g;
    *reinterpret_cast<float4*>(op)     = o0;
    *reinterpret_cast<float4*>(op + 4) = o1;
}

// ---- GEMM body (16x16x32 MFMA, counted-vmcnt pipeline, NBUF=2 or 3) --------
// C[M][N] = A[M][KTOT] @ B[KTOT][N], B given as B^T rows (N rows, K contig).
// 4 waves 2x2, wave tile (BM/2)x(BN/2). Grid 1D, bijective XCD swizzle.
// EPI: 0 plain bf16   1 S-layout bf16   2 relu h+out   3 bf16 partial Zp[bz]
//      4 chain1: Lcat col 1024+ AND transposed copy into (bf16*)Cf
//      6 chain2: Lcat col 2048 + kb_*1024
// BADDR: 0 = BT rows; 1 = feature split x|h; 2 = chain2 (kb_ picks BT/B2).
// ZK: per-bz K offset.
template<int BM, int BN, int GX, int GY, int GZ, int KTOT,
         int EPI, int BADDR, int ZK, int DEC, int NBUF>
__device__ __forceinline__
void gemm_body(const bf16_t* __restrict__ A, int lda,
               const bf16_t* __restrict__ BT, int ldbt,
               const bf16_t* __restrict__ B2,
               bf16_t* __restrict__ Cb, float* __restrict__ Cf,
               int ldc, int t)
{
    constexpr int BK = 64;
    constexpr int WM = BM / 2, WN = BN / 2;
    constexpr int MF = WM / 16, NF = WN / 16;
    constexpr int NT = KTOT / BK;
    constexpr int NWG = GX * GY * GZ;
    constexpr int ACH = BM * 8;
    constexpr int BCH = BN * 8;
    constexpr int LPT = (ACH + BCH) / 256;

    __shared__ __align__(16) bf16_t As[NBUF][BM * BK];
    __shared__ __align__(16) bf16_t Bs[NBUF][BN * BK];

    const int tid  = threadIdx.x;
    const int lane = tid & 63;
    const int wave = tid >> 6;
    const int wm = wave >> 1, wn = wave & 1;

    const int id  = blockIdx.x;
    const int swz = (id & 7) * (NWG / 8) + (id >> 3);
    int bx, by, bz;
    if (DEC == 0) {
        bx = swz % GX; by = (swz / GX) % GY; bz = swz / (GX * GY);
    } else {
        by = swz % GY; bz = (swz / GY) % GZ; bx = swz / (GY * GZ);
    }

    const int m0 = by * BM;
    const int c0 = bx * BN;
    const int kb_ = bz;

    const bf16_t* Ap = (EPI == 1) ? (A + kb_ * 128 * 256) : A;

    f32x4 acc[MF][NF] = {};

    auto stage = [&](int bufi, int kt) {
        const int q0 = kt * BK + (ZK > 0 ? kb_ * ZK : 0);
        #pragma unroll
        for (int i = 0; i < ACH / 256; ++i) {
            int chunk = i * 256 + tid;
            int off = chunk * 16;
            int row = off >> 7;
            int kel = ((off ^ ((row & 7) << 4)) & 127) >> 1;
            const bf16_t* src = Ap + (size_t)(m0 + row) * lda + (q0 + kel);
            gload_lds16(src, (char*)(&As[bufi][0]) + off);
        }
        #pragma unroll
        for (int i = 0; i < BCH / 256; ++i) {
            int chunk = i * 256 + tid;
            int off = chunk * 16;
            int row = off >> 7;
            int kel = ((off ^ ((row & 7) << 4)) & 127) >> 1;
            int c = c0 + row;
            const bf16_t* src;
            if (BADDR == 0) {
                src = BT + (size_t)c * ldbt + (q0 + kel);
            } else if (BADDR == 2) {
                const bf16_t* bt = (kb_ == 0) ? BT : B2;
                src = bt + (size_t)c * ldbt + (q0 + kel);
            } else {
                int f = q0 + kel;
                if (q0 < 128) {
                    src = BT + (size_t)(c >> 10) * 2097152
                             + (size_t)t * 131072
                             + (size_t)(c & 1023) * 128 + f;
                } else {
                    src = B2 + (size_t)c * 128 + (f - 128);
                }
            }
            gload_lds16(src, (char*)(&Bs[bufi][0]) + off);
        }
    };

    auto compute = [&](int cur) {
        #pragma unroll
        for (int kk = 0; kk < 2; ++kk) {
            bf16x8 af[MF], bfr[NF];
            const int klane = (kk * 32 + (lane >> 4) * 8) * 2;
            #pragma unroll
            for (int mf = 0; mf < MF; ++mf) {
                int row = wm * WM + mf * 16 + (lane & 15);
                int bo = (row * 128 + klane) ^ ((row & 7) << 4);
                af[mf] = *reinterpret_cast<const bf16x8*>(
                             (const char*)(&As[cur][0]) + bo);
            }
            #pragma unroll
            for (int nf = 0; nf < NF; ++nf) {
                int row = wn * WN + nf * 16 + (lane & 15);
                int bo = (row * 128 + klane) ^ ((row & 7) << 4);
                bfr[nf] = *reinterpret_cast<const bf16x8*>(
                              (const char*)(&Bs[cur][0]) + bo);
            }
            #pragma unroll
            for (int mf = 0; mf < MF; ++mf)
                #pragma unroll
                for (int nf = 0; nf < NF; ++nf)
                    acc[mf][nf] = __builtin_amdgcn_mfma_f32_16x16x32_bf16(
                        af[mf], bfr[nf], acc[mf][nf], 0, 0, 0);
        }
    };

    if constexpr (NBUF == 3) {
        stage(0, 0);
        stage(1, 1);
        for (int kt = 0; kt < NT; ++kt) {
            if (kt < NT - 1) wait_vmcnt<LPT>(); else wait_vmcnt<0>();
            __builtin_amdgcn_s_barrier();
            __builtin_amdgcn_sched_barrier(0);
            if (kt + 2 < NT) stage((kt + 2) % 3, kt + 2);
            compute(kt % 3);
            __builtin_amdgcn_sched_barrier(0);
        }
    } else {
        stage(0, 0);
        stage(1, 1);
        for (int kt = 0; kt < NT; ++kt) {
            if (kt > 0 && kt + 1 < NT) {
                __builtin_amdgcn_s_barrier();
                stage((kt + 1) & 1, kt + 1);
            }
            if (kt + 1 < NT) wait_vmcnt<LPT>();
            else             wait_vmcnt<0>();
            __builtin_amdgcn_s_barrier();
            __builtin_amdgcn_sched_barrier(0);
            compute(kt & 1);
            __builtin_amdgcn_sched_barrier(0);
        }
    }

    // epilogue: 16x16 D map col=lane&15, row=(lane>>4)*4+r  [m89-verified]
    #pragma unroll
    for (int mf = 0; mf < MF; ++mf) {
        #pragma unroll
        for (int nf = 0; nf < NF; ++nf) {
            f32x4 v = acc[mf][nf];
            int col   = c0 + wn * WN + nf * 16 + (lane & 15);
            int rbase = m0 + wm * WM + mf * 16 + ((lane >> 4) * 4);
            if constexpr (EPI == 4) {
                bf16x4 tv;
                #pragma unroll
                for (int r = 0; r < 4; ++r) {
                    float val = v[r];
                    Cb[(size_t)(rbase + r) * 4096 + 1024 + col] = (bf16_t)val;
                    tv[r] = (bf16_t)val;
                }
                *reinterpret_cast<bf16x4*>(
                    (bf16_t*)Cf + (size_t)col * 1024 + rbase) = tv;
            } else {
                #pragma unroll
                for (int r = 0; r < 4; ++r) {
                    int row = rbase + r;
                    float val = v[r];
                    if (EPI == 0) {
                        Cb[(size_t)row * ldc + col] = (bf16_t)val;
                    } else if (EPI == 1) {
                        Cb[(size_t)(col >> 10) * 524288 + (size_t)row * 4096
                           + (size_t)kb_ * 1024 + (col & 1023)] = (bf16_t)val;
                    } else if (EPI == 2) {
                        val = fmaxf(val, 0.f);
                        int b = col >> 7, g = col & 127;
                        Cb[(size_t)b * 131072 + (size_t)row * 128 + g]
                            = (bf16_t)val;
                        Cf[(size_t)b * 2097152 + (size_t)t * 131072
                           + (size_t)row * 128 + g] = val;
                    } else if (EPI == 3) {
                        Cb[(size_t)kb_ * 1048576 + (size_t)row * 1024 + col]
                            = (bf16_t)val;
                    } else {
                        // EPI == 6: chain2 -> Lcat cols 2048 + kb_*1024
                        Cb[(size_t)row * 4096 + 2048 + kb_ * 1024 + col]
                            = (bf16_t)val;
                    }
                }
            }
        }
    }
}

// ---- flavor wrappers --------------------------------------------------------

__global__ __launch_bounds__(256)
void k_chain(const bf16_t* __restrict__ A, const bf16_t* __restrict__ BT,
             bf16_t* __restrict__ Cb) {
    gemm_body<64, 64, 16, 16, 1, 1024, 0, 0, 0, 0, 3>(
        A, 4096, BT, 1024, nullptr, Cb, nullptr, 4096, 0);
}

__global__ __launch_bounds__(256)
void k_chain1(const bf16_t* __restrict__ Lcat, const bf16_t* __restrict__ Lt,
              bf16_t* __restrict__ Cb, bf16_t* __restrict__ Lt2) {
    // L^2 = L @ L -> Lcat cols [1024,2048) + Lt2 = (L^2)^T; grid 256
    gemm_body<64, 64, 16, 16, 1, 1024, 4, 0, 0, 0, 3>(
        Lcat, 4096, Lt, 1024, nullptr, Cb, (float*)Lt2, 0, 0);
}

__global__ __launch_bounds__(256)
void k_chain2(const bf16_t* __restrict__ A, const bf16_t* __restrict__ Lt,
              const bf16_t* __restrict__ Lt2, bf16_t* __restrict__ Cb) {
    // bz=0: L^3 = L^2 @ L;  bz=1: L^4 = L^2 @ L^2; grid 512 (2 blk/CU)
    gemm_body<64, 64, 16, 16, 2, 1024, 6, 2, 0, 0, 3>(
        A, 4096, Lt, 1024, Lt2, Cb, nullptr, 0, 0);
}

__global__ __launch_bounds__(256)
void k_feat(const bf16_t* __restrict__ WHT, const bf16_t* __restrict__ xb,
            const bf16_t* __restrict__ h, bf16_t* __restrict__ Sbuf, int t) {
    // M=128,N=8192,K=256 per tap; 128x64 tiles, grid 128*1*4 = 512
    gemm_body<128, 64, 128, 1, 4, 256, 1, 1, 0, 1, 3>(
        WHT, 256, xb, 0, h, Sbuf, nullptr, 0, t);
}

__global__ __launch_bounds__(256)
void k_graph(const bf16_t* __restrict__ Lcat, const bf16_t* __restrict__ Sbuf,
             bf16_t* __restrict__ Zp) {
    // M=1024,N=1024, split-K=8 (K=512/slice, one slice per XCD);
    // 128x128 tiles / 64x64 waves, grid 512, 2-buf, bf16 partials
    gemm_body<128, 128, 8, 8, 8, 512, 3, 0, 512, 0, 2>(
        Lcat, 4096, Sbuf, 4096, nullptr, Zp, nullptr, 0, 0);
}

__global__ __launch_bounds__(256)
void k_graph_ns(const bf16_t* __restrict__ Lcat, const bf16_t* __restrict__ Sbuf,
                bf16_t* __restrict__ h, float* __restrict__ out, int t) {
    // fallback: no split-K, K=4096; 128x128 tiles, grid 64, 3-buf
    gemm_body<128, 128, 8, 8, 1, 4096, 2, 0, 0, 0, 3>(
        Lcat, 4096, Sbuf, 4096, nullptr, h, out, 0, t);
}

// ---- launch ---------------------------------------------------------------

extern "C" void kernel_launch(void* const* d_in, const int* in_sizes, int n_in,
                              void* d_out, int out_size, void* d_ws, size_t ws_size,
                              hipStream_t stream) {
    const float* x = (const float*)d_in[0];   // [8][16][1024][128]
    const float* L = (const float*)d_in[1];   // [1024][1024]
    const float* W = (const float*)d_in[2];   // [4][128][128]
    const float* H = (const float*)d_in[3];   // [4][128][128]
    float* out = (float*)d_out;               // [8][16][1024][128]

    char* ws = (char*)d_ws;
    bf16_t* xb   = (bf16_t*)(ws);              // 33,554,432 B
    bf16_t* Lcat = (bf16_t*)(ws + 33554432);   //  8,388,608 B [1024][4096]
    bf16_t* Lt   = (bf16_t*)(ws + 41943040);   //  2,097,152 B
    bf16_t* WHT  = (bf16_t*)(ws + 44040192);   //    262,144 B
    bf16_t* Sbuf = (bf16_t*)(ws + 44302336);   //  8,388,608 B (S layout)
    bf16_t* h    = (bf16_t*)(ws + 52690944);   //  2,097,152 B
    bf16_t* Zp   = (bf16_t*)(ws + 54788096);   // 16,777,216 B [8][1024][1024]
    bf16_t* Lt2  = (bf16_t*)(ws + 71565312);   //  2,097,152 B (L^2)^T
    if (ws_size < 54788096u) return;
    const bool bigws = (ws_size >= 73662464u);

    hipMemsetAsync(h, 0, 2097152, stream);
    k_setup<<<8448, 256, 0, stream>>>(x, L, W, H, xb, Lcat, Lt, WHT);

    if (bigws) {
        // chain: L^2 (+transpose), then {L^3, L^4} concurrently
        k_chain1<<<256, 256, 0, stream>>>(Lcat, Lt, Lcat, Lt2);
        k_chain2<<<512, 256, 0, stream>>>(Lcat + 1024, Lt, Lt2, Lcat);
        for (int t = 0; t < 16; ++t) {
            // feature: S_k = WHT_k @ [x_t | h]^T, 512 WGs
            k_feat<<<512, 256, 0, stream>>>(WHT, xb, h, Sbuf, t);
            // graph: Zp[z] = Lcat[:,z*512:+512] @ S[z], split-K=8, 512 WGs
            k_graph<<<512, 256, 0, stream>>>(Lcat, Sbuf, Zp);
            // combine: relu(sum Zp) -> h, out
            k_combine8<<<512, 256, 0, stream>>>(Zp, h, out, t);
        }
    } else {
        for (int p = 1; p < 4; ++p) {
            k_chain<<<256, 256, 0, stream>>>(Lcat + (p - 1) * 1024, Lt,
                                             Lcat + p * 1024);
        }
        for (int t = 0; t < 16; ++t) {
            k_feat<<<512, 256, 0, stream>>>(WHT, xb, h, Sbuf, t);
            k_graph_ns<<<64, 256, 0, stream>>>(Lcat, Sbuf, h, out, t);
        }
    }
}